// Round 6
// baseline (118.657 us; speedup 1.0000x reference)
//
#include <hip/hip_runtime.h>
#include <math.h>

// NeRF two-pass renderer. One wave (64 lanes) per ray; 4 waves per block.
// B=65536 rays, KC=64 coarse, KF=64 fine, HID=32.
//
// R6 = R5 + analytic merge ranks (step-space):
//  - fine key = cnt + uj (bitwise == ref z_steps*64); bitonic sorts key.
//  - g = cnt' + (uc[cnt'] <= uj')  (1 bpermute) replaces the 7-step
//    "#coarse <= zf" search; pos_f = lane + g.
//  - pos_c = lane + #{g <= lane} via per-wave LDS histogram of g + DPP
//    inclusive scan (replaces the 7-step "#fine < zc" search).
//  - everything else as R5 (packed fp32 MLP, DPP scans/reductions,
//    coarse-output reuse, unnormalized cdf searchsorted).

typedef float f32x2 __attribute__((ext_vector_type(2)));

__device__ __forceinline__ float fast_rcp(float x) { return __builtin_amdgcn_rcpf(x); }
__device__ __forceinline__ float fsigmoid(float x) { return fast_rcp(1.0f + __expf(-x)); }

__device__ __forceinline__ f32x2 splat_lo(f32x2 v) { return __builtin_shufflevector(v, v, 0, 0); }
__device__ __forceinline__ f32x2 splat_hi(f32x2 v) { return __builtin_shufflevector(v, v, 1, 1); }

// DPP move: result = valid(src lane) ? shuffled x : oldv   (bound_ctrl=0)
template <int CTRL, int RMASK>
__device__ __forceinline__ float dpp_f(float x, float oldv) {
    return __int_as_float(__builtin_amdgcn_update_dpp(
        __float_as_int(oldv), __float_as_int(x), CTRL, RMASK, 0xf, false));
}
template <int CTRL, int RMASK>
__device__ __forceinline__ int dpp_i(int x, int oldv) {
    return __builtin_amdgcn_update_dpp(oldv, x, CTRL, RMASK, 0xf, false);
}

// inclusive multiply-scan over 64 lanes (lane i = prod_{j<=i})
__device__ __forceinline__ float scan_mul(float x) {
    x *= dpp_f<0x111, 0xf>(x, 1.0f);  // row_shr:1
    x *= dpp_f<0x112, 0xf>(x, 1.0f);  // row_shr:2
    x *= dpp_f<0x114, 0xf>(x, 1.0f);  // row_shr:4
    x *= dpp_f<0x118, 0xf>(x, 1.0f);  // row_shr:8
    x *= dpp_f<0x142, 0xa>(x, 1.0f);  // row_bcast:15 -> rows 1,3
    x *= dpp_f<0x143, 0xc>(x, 1.0f);  // row_bcast:31 -> rows 2,3
    return x;
}
// inclusive add-scan over 64 lanes; lane 63 holds the full sum
__device__ __forceinline__ float scan_add(float x) {
    x += dpp_f<0x111, 0xf>(x, 0.0f);
    x += dpp_f<0x112, 0xf>(x, 0.0f);
    x += dpp_f<0x114, 0xf>(x, 0.0f);
    x += dpp_f<0x118, 0xf>(x, 0.0f);
    x += dpp_f<0x142, 0xa>(x, 0.0f);
    x += dpp_f<0x143, 0xc>(x, 0.0f);
    return x;
}
__device__ __forceinline__ int scan_add_i(int x) {
    x += dpp_i<0x111, 0xf>(x, 0);
    x += dpp_i<0x112, 0xf>(x, 0);
    x += dpp_i<0x114, 0xf>(x, 0);
    x += dpp_i<0x118, 0xf>(x, 0);
    x += dpp_i<0x142, 0xa>(x, 0);
    x += dpp_i<0x143, 0xc>(x, 0);
    return x;
}

__global__ __launch_bounds__(256) void nerf_render(
    const float* __restrict__ rays,      // (B,8)  o(3) d(3) near far
    const float* __restrict__ u_coarse,  // (B,64)
    const float* __restrict__ u_fine,    // (B,64)
    const float* __restrict__ u_jitter,  // (B,64)
    const float* __restrict__ W1,        // (3,32)
    const float* __restrict__ b1,        // (32,)
    const float* __restrict__ W2,        // (32,4)
    const float* __restrict__ b2,        // (4,)
    float* __restrict__ out)             // (B,8)  rgb_f, depth_f, rgb_c, depth_c
{
    __shared__ float acS[4][64];     // per wave: a[0..31], c[0..31]
    __shared__ float mS[4][5][128];  // per wave merged: z, r, g, b, sigma
    __shared__ unsigned int histS[4][65];  // per wave: histogram of g (g=64 slot ignored)

    const int lane = threadIdx.x & 63;
    const int wv   = threadIdx.x >> 6;
    const int ray  = (blockIdx.x << 2) + wv;

    const float* rp = rays + ray * 8;
    const float ox = rp[0], oy = rp[1], oz = rp[2];
    const float ddx = rp[3], ddy = rp[4], ddz = rp[5];
    const float nearv = rp[6], farv = rp[7];

    // cooperative a/c: lanes 0..31 -> a[j] = o@W1+b1, lanes 32..63 -> c[j] = d@W1
    {
        const int j = lane & 31;
        const float w0 = W1[j], w1 = W1[32 + j], w2 = W1[64 + j];
        const bool isA = lane < 32;
        const float px = isA ? ox : ddx;
        const float py = isA ? oy : ddy;
        const float pz = isA ? oz : ddz;
        const float bb = isA ? b1[j] : 0.0f;
        acS[wv][lane] = fmaf(px, w0, fmaf(py, w1, fmaf(pz, w2, bb)));
    }
    __syncthreads();

    const float* __restrict__ aw = &acS[wv][0];
    const float* __restrict__ cw = &acS[wv][32];

    // h = relu(a + z*c) (32); out4 = h @ W2 + b2; rgb=sigmoid, sigma raw.
    auto mlp = [&](float z, float& rr, float& gg, float& bb_, float& sg) {
        const f32x2 zz = {z, z};
        const f32x2 zero2 = {0.0f, 0.0f};
        f32x2 acc01 = *reinterpret_cast<const f32x2*>(b2);
        f32x2 acc23 = *reinterpret_cast<const f32x2*>(b2 + 2);
#pragma unroll
        for (int j = 0; j < 32; j += 4) {
            const f32x2 a01 = *reinterpret_cast<const f32x2*>(aw + j);
            const f32x2 a23 = *reinterpret_cast<const f32x2*>(aw + j + 2);
            const f32x2 c01 = *reinterpret_cast<const f32x2*>(cw + j);
            const f32x2 c23 = *reinterpret_cast<const f32x2*>(cw + j + 2);
            f32x2 h01 = __builtin_elementwise_fma(zz, c01, a01);
            f32x2 h23 = __builtin_elementwise_fma(zz, c23, a23);
            h01 = __builtin_elementwise_max(h01, zero2);
            h23 = __builtin_elementwise_max(h23, zero2);
            {
                const f32x2 wA = *reinterpret_cast<const f32x2*>(W2 + (j + 0) * 4);
                const f32x2 wB = *reinterpret_cast<const f32x2*>(W2 + (j + 0) * 4 + 2);
                const f32x2 hs = splat_lo(h01);
                acc01 = __builtin_elementwise_fma(hs, wA, acc01);
                acc23 = __builtin_elementwise_fma(hs, wB, acc23);
            }
            {
                const f32x2 wA = *reinterpret_cast<const f32x2*>(W2 + (j + 1) * 4);
                const f32x2 wB = *reinterpret_cast<const f32x2*>(W2 + (j + 1) * 4 + 2);
                const f32x2 hs = splat_hi(h01);
                acc01 = __builtin_elementwise_fma(hs, wA, acc01);
                acc23 = __builtin_elementwise_fma(hs, wB, acc23);
            }
            {
                const f32x2 wA = *reinterpret_cast<const f32x2*>(W2 + (j + 2) * 4);
                const f32x2 wB = *reinterpret_cast<const f32x2*>(W2 + (j + 2) * 4 + 2);
                const f32x2 hs = splat_lo(h23);
                acc01 = __builtin_elementwise_fma(hs, wA, acc01);
                acc23 = __builtin_elementwise_fma(hs, wB, acc23);
            }
            {
                const f32x2 wA = *reinterpret_cast<const f32x2*>(W2 + (j + 3) * 4);
                const f32x2 wB = *reinterpret_cast<const f32x2*>(W2 + (j + 3) * 4 + 2);
                const f32x2 hs = splat_hi(h23);
                acc01 = __builtin_elementwise_fma(hs, wA, acc01);
                acc23 = __builtin_elementwise_fma(hs, wB, acc23);
            }
        }
        rr = fsigmoid(acc01.x); gg = fsigmoid(acc01.y);
        bb_ = fsigmoid(acc23.x); sg = acc23.y;
    };

    // ---------------- coarse pass ----------------
    const float uc = u_coarse[ray * 64 + lane];
    const float zsc = (float)lane * 0.015625f + uc * 0.015625f;  // bit-match ref
    const float zc = nearv * (1.0f - zsc) + farv * zsc;

    const float zcn = __shfl_down(zc, 1);
    const float deltac = (lane == 63) ? (farv - zc) : (zcn - zc);

    float cr_, cg_, cb_, csig;
    mlp(zc, cr_, cg_, cb_, csig);
    const float alphac = 1.0f - __expf(-deltac * fmaxf(csig, 0.0f));
    const float sc = 1.0f - alphac + 1e-10f;

    // exclusive prefix product -> transmittance (DPP inclusive scan + shift)
    const float pincl = scan_mul(sc);
    float Tc = __shfl_up(pincl, 1);
    if (lane == 0) Tc = 1.0f;
    const float wc = alphac * Tc;

    // coarse outputs: DPP reduce, totals land in lane 63
    const float rc = scan_add(wc * cr_);
    const float gc = scan_add(wc * cg_);
    const float bc = scan_add(wc * cb_);
    const float dc = scan_add(wc * zc);

    // ---------------- fine sampling (inverse CDF, unnormalized) ----------------
    const float wp = wc + 1e-5f;
    const float cdf = scan_add(wp);  // inclusive prefix sum
    const float tot = __int_as_float(__builtin_amdgcn_readlane(__float_as_int(cdf), 63));

    const float uf = u_fine[ray * 64 + lane] * tot;  // compare in unnormalized space
    // cnt = #{k: cdf_incl[k] <= u} == searchsorted_right(cdf0, u) - 1, clamped
    int cnt = 0;
#pragma unroll
    for (int step = 64; step >= 1; step >>= 1) {
        const int idx = cnt + step - 1;
        const float v = __shfl(cdf, idx < 64 ? idx : 63);
        if (idx < 64 && v <= uf) cnt += step;
    }
    const float uj = u_jitter[ray * 64 + lane];
    float key = (float)cnt + uj;  // == ref z_steps * 64 (bitwise)

    // ---------------- sort fine keys (bitonic, 64 lanes; DPP for j=1,2) ----------------
#pragma unroll
    for (int k = 2; k <= 64; k <<= 1) {
#pragma unroll
        for (int j = k >> 1; j > 0; j >>= 1) {
            float v;
            if (j == 1)      v = dpp_f<0xB1, 0xf>(key, key);  // quad_perm [1,0,3,2]
            else if (j == 2) v = dpp_f<0x4E, 0xf>(key, key);  // quad_perm [2,3,0,1]
            else             v = __shfl_xor(key, j);
            const bool keepMin = (((lane & j) == 0) == ((lane & k) == 0));
            key = keepMin ? fminf(key, v) : fmaxf(key, v);
        }
    }

    // ---------------- analytic merge ranks (step-space) ----------------
    // reconstruct cnt', uj' from sorted key; g = #{coarse before this fine}
    int cnti = (int)key; cnti = cnti > 63 ? 63 : cnti;
    const float ujr = key - (float)cnti;
    const float ucv = __shfl(uc, cnti);            // u_coarse[cnt'] (1 bpermute)
    const int g = cnti + ((ucv <= ujr) ? 1 : 0);   // fine k before coarse l <=> l >= g
    const int pos_f = lane + g;                    // sorted rank + coarse-before count

    // pos_c = lane + #{k: g_k <= lane} via per-wave histogram + inclusive scan
    histS[wv][lane] = 0u;
    __syncthreads();  // embedded lgkmcnt(0): zeros visible before atomics
    atomicAdd(&histS[wv][g], 1u);   // g==64 lands in ignored slot 64
    __syncthreads();  // atomics complete before reads
    const int cfv = scan_add_i((int)histS[wv][lane]);  // inclusive: #{g <= lane}
    const int pos_c = lane + cfv;

    // fine z + MLP (coarse outputs reused, not recomputed)
    const float zsf = key * 0.015625f;
    const float zf = nearv * (1.0f - zsf) + farv * zsf;
    float fr_, fg_, fb_, fsig;
    mlp(zf, fr_, fg_, fb_, fsig);

    // ---------------- scatter merged (z, r, g, b, sigma) ----------------
    {
        mS[wv][0][pos_c] = zc;   mS[wv][0][pos_f] = zf;
        mS[wv][1][pos_c] = cr_;  mS[wv][1][pos_f] = fr_;
        mS[wv][2][pos_c] = cg_;  mS[wv][2][pos_f] = fg_;
        mS[wv][3][pos_c] = cb_;  mS[wv][3][pos_f] = fb_;
        mS[wv][4][pos_c] = csig; mS[wv][4][pos_f] = fsig;
    }
    __syncthreads();

    // ---------------- fine composite (2 samples / lane) ----------------
    const float2 zz2 = *reinterpret_cast<const float2*>(&mS[wv][0][2 * lane]);
    const float z0 = zz2.x, z1 = zz2.y;
    const float z2n = mS[wv][0][(2 * lane + 2) & 127];
    const float2 rr2 = *reinterpret_cast<const float2*>(&mS[wv][1][2 * lane]);
    const float2 gg2 = *reinterpret_cast<const float2*>(&mS[wv][2][2 * lane]);
    const float2 bb2 = *reinterpret_cast<const float2*>(&mS[wv][3][2 * lane]);
    const float2 ss2 = *reinterpret_cast<const float2*>(&mS[wv][4][2 * lane]);

    const float d0 = z1 - z0;
    const float d1 = (lane == 63) ? (farv - z1) : (z2n - z1);

    const float al0 = 1.0f - __expf(-d0 * fmaxf(ss2.x, 0.0f));
    const float al1 = 1.0f - __expf(-d1 * fmaxf(ss2.y, 0.0f));
    const float t0 = 1.0f - al0 + 1e-10f;
    const float t1 = 1.0f - al1 + 1e-10f;

    // pair product, DPP inclusive scan, exclusive via shift
    const float ppincl = scan_mul(t0 * t1);
    float Te = __shfl_up(ppincl, 1);
    if (lane == 0) Te = 1.0f;
    const float w0 = al0 * Te;
    const float w1 = al1 * (Te * t0);

    // fine outputs: DPP reduce to lane 63
    const float fr = scan_add(fmaf(w0, rr2.x, w1 * rr2.y));
    const float fg = scan_add(fmaf(w0, gg2.x, w1 * gg2.y));
    const float fb = scan_add(fmaf(w0, bb2.x, w1 * bb2.y));
    const float fd = scan_add(fmaf(w0, z0, w1 * z1));

    if (lane == 63) {
        float4* op = reinterpret_cast<float4*>(out + ray * 8);
        op[0] = make_float4(fr, fg, fb, fd);
        op[1] = make_float4(rc, gc, bc, dc);
    }
}

extern "C" void kernel_launch(void* const* d_in, const int* in_sizes, int n_in,
                              void* d_out, int out_size, void* d_ws, size_t ws_size,
                              hipStream_t stream) {
    const float* rays     = (const float*)d_in[0];
    const float* u_coarse = (const float*)d_in[1];
    const float* u_fine   = (const float*)d_in[2];
    const float* u_jitter = (const float*)d_in[3];
    const float* W1       = (const float*)d_in[4];
    const float* b1       = (const float*)d_in[5];
    const float* W2       = (const float*)d_in[6];
    const float* b2       = (const float*)d_in[7];
    float* out = (float*)d_out;

    const int B = in_sizes[0] / 8;          // 65536
    dim3 grid(B / 4), block(256);           // one wave per ray, 4 waves/block
    hipLaunchKernelGGL(nerf_render, grid, block, 0, stream,
                       rays, u_coarse, u_fine, u_jitter, W1, b1, W2, b2, out);
}

// Round 7
// 81.066 us; speedup vs baseline: 1.4637x; 1.4637x over previous
//
#include <hip/hip_runtime.h>
#include <math.h>

// NeRF two-pass renderer. One wave (64 lanes) per ray; 4 waves per block.
// B=65536 rays, KC=64 coarse, KF=64 fine, HID=32.
//
// R7 = R6 + occupancy unlock:
//  - LDS 12800 -> 7168 B/block: merged r,g,b,sigma packed as _Float16 pairs;
//    histogram overlaid on the z array (used strictly before z scatter).
//  - all __syncthreads removed: every LDS region is wave-private (written and
//    read only by its own wave); per-wave DS ops are HW-ordered, so only
//    compiler reordering must be fenced (wave_barrier + memory clobber).
//  - exclusive shift via DPP wave_shr:1 / wave_shl:1 (no bpermute, no branch).
//  - everything else as R6 (packed fp32 MLP, DPP scans, analytic merge ranks,
//    coarse-output reuse, unnormalized cdf searchsorted).

typedef float f32x2 __attribute__((ext_vector_type(2)));
typedef _Float16 f16x2v __attribute__((ext_vector_type(2)));
typedef _Float16 f16x4v __attribute__((ext_vector_type(4)));

__device__ __forceinline__ float fast_rcp(float x) { return __builtin_amdgcn_rcpf(x); }
__device__ __forceinline__ float fsigmoid(float x) { return fast_rcp(1.0f + __expf(-x)); }

__device__ __forceinline__ f32x2 splat_lo(f32x2 v) { return __builtin_shufflevector(v, v, 0, 0); }
__device__ __forceinline__ f32x2 splat_hi(f32x2 v) { return __builtin_shufflevector(v, v, 1, 1); }

// compiler-only fence: no HW barrier; preserves LDS program order per wave
__device__ __forceinline__ void wave_fence() {
    asm volatile("" ::: "memory");
    __builtin_amdgcn_wave_barrier();
}

// DPP move: result = valid(src lane) ? shuffled x : oldv   (bound_ctrl=0)
template <int CTRL, int RMASK>
__device__ __forceinline__ float dpp_f(float x, float oldv) {
    return __int_as_float(__builtin_amdgcn_update_dpp(
        __float_as_int(oldv), __float_as_int(x), CTRL, RMASK, 0xf, false));
}
template <int CTRL, int RMASK>
__device__ __forceinline__ int dpp_i(int x, int oldv) {
    return __builtin_amdgcn_update_dpp(oldv, x, CTRL, RMASK, 0xf, false);
}

// inclusive multiply-scan over 64 lanes (lane i = prod_{j<=i})
__device__ __forceinline__ float scan_mul(float x) {
    x *= dpp_f<0x111, 0xf>(x, 1.0f);  // row_shr:1
    x *= dpp_f<0x112, 0xf>(x, 1.0f);  // row_shr:2
    x *= dpp_f<0x114, 0xf>(x, 1.0f);  // row_shr:4
    x *= dpp_f<0x118, 0xf>(x, 1.0f);  // row_shr:8
    x *= dpp_f<0x142, 0xa>(x, 1.0f);  // row_bcast:15 -> rows 1,3
    x *= dpp_f<0x143, 0xc>(x, 1.0f);  // row_bcast:31 -> rows 2,3
    return x;
}
// inclusive add-scan over 64 lanes; lane 63 holds the full sum
__device__ __forceinline__ float scan_add(float x) {
    x += dpp_f<0x111, 0xf>(x, 0.0f);
    x += dpp_f<0x112, 0xf>(x, 0.0f);
    x += dpp_f<0x114, 0xf>(x, 0.0f);
    x += dpp_f<0x118, 0xf>(x, 0.0f);
    x += dpp_f<0x142, 0xa>(x, 0.0f);
    x += dpp_f<0x143, 0xc>(x, 0.0f);
    return x;
}
__device__ __forceinline__ int scan_add_i(int x) {
    x += dpp_i<0x111, 0xf>(x, 0);
    x += dpp_i<0x112, 0xf>(x, 0);
    x += dpp_i<0x114, 0xf>(x, 0);
    x += dpp_i<0x118, 0xf>(x, 0);
    x += dpp_i<0x142, 0xa>(x, 0);
    x += dpp_i<0x143, 0xc>(x, 0);
    return x;
}

__global__ __launch_bounds__(256) void nerf_render(
    const float* __restrict__ rays,      // (B,8)  o(3) d(3) near far
    const float* __restrict__ u_coarse,  // (B,64)
    const float* __restrict__ u_fine,    // (B,64)
    const float* __restrict__ u_jitter,  // (B,64)
    const float* __restrict__ W1,        // (3,32)
    const float* __restrict__ b1,        // (32,)
    const float* __restrict__ W2,        // (32,4)
    const float* __restrict__ b2,        // (4,)
    float* __restrict__ out)             // (B,8)  rgb_f, depth_f, rgb_c, depth_c
{
    __shared__ float  acS[4][64];    // per wave: a[0..31], c[0..31]      1024B
    __shared__ float  zM[4][128];    // per wave merged z; hist overlay   2048B
    __shared__ f16x2v rgM[4][128];   // per wave merged (r,g) half2       2048B
    __shared__ f16x2v bsM[4][128];   // per wave merged (b,sigma) half2   2048B

    const int lane = threadIdx.x & 63;
    const int wv   = threadIdx.x >> 6;
    const int ray  = (blockIdx.x << 2) + wv;

    const float* rp = rays + ray * 8;
    const float ox = rp[0], oy = rp[1], oz = rp[2];
    const float ddx = rp[3], ddy = rp[4], ddz = rp[5];
    const float nearv = rp[6], farv = rp[7];

    // cooperative a/c: lanes 0..31 -> a[j] = o@W1+b1, lanes 32..63 -> c[j] = d@W1
    {
        const int j = lane & 31;
        const float w0 = W1[j], w1 = W1[32 + j], w2 = W1[64 + j];
        const bool isA = lane < 32;
        const float px = isA ? ox : ddx;
        const float py = isA ? oy : ddy;
        const float pz = isA ? oz : ddz;
        const float bb = isA ? b1[j] : 0.0f;
        acS[wv][lane] = fmaf(px, w0, fmaf(py, w1, fmaf(pz, w2, bb)));
    }
    wave_fence();  // wave-private region: HW per-wave DS order suffices

    const float* aw = &acS[wv][0];
    const float* cw = &acS[wv][32];

    // h = relu(a + z*c) (32); out4 = h @ W2 + b2; rgb=sigmoid, sigma raw.
    auto mlp = [&](float z, float& rr, float& gg, float& bb_, float& sg) {
        const f32x2 zz = {z, z};
        const f32x2 zero2 = {0.0f, 0.0f};
        f32x2 acc01 = *reinterpret_cast<const f32x2*>(b2);
        f32x2 acc23 = *reinterpret_cast<const f32x2*>(b2 + 2);
#pragma unroll
        for (int j = 0; j < 32; j += 4) {
            const f32x2 a01 = *reinterpret_cast<const f32x2*>(aw + j);
            const f32x2 a23 = *reinterpret_cast<const f32x2*>(aw + j + 2);
            const f32x2 c01 = *reinterpret_cast<const f32x2*>(cw + j);
            const f32x2 c23 = *reinterpret_cast<const f32x2*>(cw + j + 2);
            f32x2 h01 = __builtin_elementwise_fma(zz, c01, a01);
            f32x2 h23 = __builtin_elementwise_fma(zz, c23, a23);
            h01 = __builtin_elementwise_max(h01, zero2);
            h23 = __builtin_elementwise_max(h23, zero2);
            {
                const f32x2 wA = *reinterpret_cast<const f32x2*>(W2 + (j + 0) * 4);
                const f32x2 wB = *reinterpret_cast<const f32x2*>(W2 + (j + 0) * 4 + 2);
                const f32x2 hs = splat_lo(h01);
                acc01 = __builtin_elementwise_fma(hs, wA, acc01);
                acc23 = __builtin_elementwise_fma(hs, wB, acc23);
            }
            {
                const f32x2 wA = *reinterpret_cast<const f32x2*>(W2 + (j + 1) * 4);
                const f32x2 wB = *reinterpret_cast<const f32x2*>(W2 + (j + 1) * 4 + 2);
                const f32x2 hs = splat_hi(h01);
                acc01 = __builtin_elementwise_fma(hs, wA, acc01);
                acc23 = __builtin_elementwise_fma(hs, wB, acc23);
            }
            {
                const f32x2 wA = *reinterpret_cast<const f32x2*>(W2 + (j + 2) * 4);
                const f32x2 wB = *reinterpret_cast<const f32x2*>(W2 + (j + 2) * 4 + 2);
                const f32x2 hs = splat_lo(h23);
                acc01 = __builtin_elementwise_fma(hs, wA, acc01);
                acc23 = __builtin_elementwise_fma(hs, wB, acc23);
            }
            {
                const f32x2 wA = *reinterpret_cast<const f32x2*>(W2 + (j + 3) * 4);
                const f32x2 wB = *reinterpret_cast<const f32x2*>(W2 + (j + 3) * 4 + 2);
                const f32x2 hs = splat_hi(h23);
                acc01 = __builtin_elementwise_fma(hs, wA, acc01);
                acc23 = __builtin_elementwise_fma(hs, wB, acc23);
            }
        }
        rr = fsigmoid(acc01.x); gg = fsigmoid(acc01.y);
        bb_ = fsigmoid(acc23.x); sg = acc23.y;
    };

    // ---------------- coarse pass ----------------
    const float uc = u_coarse[ray * 64 + lane];
    const float zsc = (float)lane * 0.015625f + uc * 0.015625f;  // bit-match ref
    const float zc = nearv * (1.0f - zsc) + farv * zsc;

    const float zcn = dpp_f<0x130, 0xf>(zc, zc);  // wave_shl:1 (lane i <- i+1)
    const float deltac = (lane == 63) ? (farv - zc) : (zcn - zc);

    float cr_, cg_, cb_, csig;
    mlp(zc, cr_, cg_, cb_, csig);
    const float alphac = 1.0f - __expf(-deltac * fmaxf(csig, 0.0f));
    const float sc = 1.0f - alphac + 1e-10f;

    // exclusive prefix product -> transmittance (DPP scan + wave_shr:1)
    const float pincl = scan_mul(sc);
    const float Tc = dpp_f<0x138, 0xf>(pincl, 1.0f);  // lane0 keeps 1.0
    const float wc = alphac * Tc;

    // coarse outputs: DPP reduce, totals land in lane 63
    const float rc = scan_add(wc * cr_);
    const float gc = scan_add(wc * cg_);
    const float bc = scan_add(wc * cb_);
    const float dc = scan_add(wc * zc);

    // ---------------- fine sampling (inverse CDF, unnormalized) ----------------
    const float wp = wc + 1e-5f;
    const float cdf = scan_add(wp);  // inclusive prefix sum
    const float tot = __int_as_float(__builtin_amdgcn_readlane(__float_as_int(cdf), 63));

    const float uf = u_fine[ray * 64 + lane] * tot;  // compare in unnormalized space
    // cnt = #{k: cdf_incl[k] <= u} == searchsorted_right(cdf0, u) - 1, clamped
    int cnt = 0;
#pragma unroll
    for (int step = 64; step >= 1; step >>= 1) {
        const int idx = cnt + step - 1;
        const float v = __shfl(cdf, idx < 64 ? idx : 63);
        if (idx < 64 && v <= uf) cnt += step;
    }
    const float uj = u_jitter[ray * 64 + lane];
    float key = (float)cnt + uj;  // == ref z_steps * 64 (bitwise)

    // ---------------- sort fine keys (bitonic, 64 lanes; DPP for j=1,2) ----------------
#pragma unroll
    for (int k = 2; k <= 64; k <<= 1) {
#pragma unroll
        for (int j = k >> 1; j > 0; j >>= 1) {
            float v;
            if (j == 1)      v = dpp_f<0xB1, 0xf>(key, key);  // quad_perm [1,0,3,2]
            else if (j == 2) v = dpp_f<0x4E, 0xf>(key, key);  // quad_perm [2,3,0,1]
            else             v = __shfl_xor(key, j);
            const bool keepMin = (((lane & j) == 0) == ((lane & k) == 0));
            key = keepMin ? fminf(key, v) : fmaxf(key, v);
        }
    }

    // ---------------- analytic merge ranks (step-space) ----------------
    // reconstruct cnt', uj' from sorted key; g = #{coarse before this fine}
    int cnti = (int)key; cnti = cnti > 63 ? 63 : cnti;
    const float ujr = key - (float)cnti;
    const float ucv = __shfl(uc, cnti);            // u_coarse[cnt'] (1 bpermute)
    const int g = cnti + ((ucv <= ujr) ? 1 : 0);   // fine k before coarse l <=> l >= g
    const int pos_f = lane + g;                    // sorted rank + coarse-before count

    // pos_c = lane + #{k: g_k <= lane}: histogram overlaid on zM (pre-scatter)
    unsigned int* hist = reinterpret_cast<unsigned int*>(&zM[wv][0]);
    hist[lane] = 0u;
    wave_fence();
    atomicAdd(&hist[g], 1u);   // g==64 lands in zM slot 64 (overwritten later)
    wave_fence();
    const int cfv = scan_add_i((int)hist[lane]);  // inclusive: #{g <= lane}
    const int pos_c = lane + cfv;
    wave_fence();  // hist reads complete before zM scatter overwrites

    // fine z + MLP (coarse outputs reused, not recomputed)
    const float zsf = key * 0.015625f;
    const float zf = nearv * (1.0f - zsf) + farv * zsf;
    float fr_, fg_, fb_, fsig;
    mlp(zf, fr_, fg_, fb_, fsig);

    // ---------------- scatter merged (z f32; r,g,b,sigma f16) ----------------
    {
        zM[wv][pos_c] = zc;
        zM[wv][pos_f] = zf;
        f16x2v t;
        t.x = (_Float16)cr_;  t.y = (_Float16)cg_;  rgM[wv][pos_c] = t;
        t.x = (_Float16)fr_;  t.y = (_Float16)fg_;  rgM[wv][pos_f] = t;
        t.x = (_Float16)cb_;  t.y = (_Float16)csig; bsM[wv][pos_c] = t;
        t.x = (_Float16)fb_;  t.y = (_Float16)fsig; bsM[wv][pos_f] = t;
    }
    wave_fence();  // wave-private: scatter precedes gather in per-wave DS order

    // ---------------- fine composite (2 samples / lane) ----------------
    const float2 zz2 = *reinterpret_cast<const float2*>(&zM[wv][2 * lane]);
    const float z0 = zz2.x, z1 = zz2.y;
    const float z2n = zM[wv][(2 * lane + 2) & 127];
    const f16x4v rg4 = *reinterpret_cast<const f16x4v*>(&rgM[wv][2 * lane]);
    const f16x4v bs4 = *reinterpret_cast<const f16x4v*>(&bsM[wv][2 * lane]);
    const float r0 = (float)rg4.x, g0 = (float)rg4.y;
    const float r1 = (float)rg4.z, g1 = (float)rg4.w;
    const float b0 = (float)bs4.x, s0 = (float)bs4.y;
    const float b1v = (float)bs4.z, s1 = (float)bs4.w;

    const float d0 = z1 - z0;
    const float d1 = (lane == 63) ? (farv - z1) : (z2n - z1);

    const float al0 = 1.0f - __expf(-d0 * fmaxf(s0, 0.0f));
    const float al1 = 1.0f - __expf(-d1 * fmaxf(s1, 0.0f));
    const float t0 = 1.0f - al0 + 1e-10f;
    const float t1 = 1.0f - al1 + 1e-10f;

    // pair product, DPP inclusive scan, exclusive via wave_shr:1
    const float ppincl = scan_mul(t0 * t1);
    const float Te = dpp_f<0x138, 0xf>(ppincl, 1.0f);  // lane0 keeps 1.0
    const float w0 = al0 * Te;
    const float w1 = al1 * (Te * t0);

    // fine outputs: DPP reduce to lane 63
    const float fr = scan_add(fmaf(w0, r0, w1 * r1));
    const float fg = scan_add(fmaf(w0, g0, w1 * g1));
    const float fb = scan_add(fmaf(w0, b0, w1 * b1v));
    const float fd = scan_add(fmaf(w0, z0, w1 * z1));

    if (lane == 63) {
        float4* op = reinterpret_cast<float4*>(out + ray * 8);
        op[0] = make_float4(fr, fg, fb, fd);
        op[1] = make_float4(rc, gc, bc, dc);
    }
}

extern "C" void kernel_launch(void* const* d_in, const int* in_sizes, int n_in,
                              void* d_out, int out_size, void* d_ws, size_t ws_size,
                              hipStream_t stream) {
    const float* rays     = (const float*)d_in[0];
    const float* u_coarse = (const float*)d_in[1];
    const float* u_fine   = (const float*)d_in[2];
    const float* u_jitter = (const float*)d_in[3];
    const float* W1       = (const float*)d_in[4];
    const float* b1       = (const float*)d_in[5];
    const float* W2       = (const float*)d_in[6];
    const float* b2       = (const float*)d_in[7];
    float* out = (float*)d_out;

    const int B = in_sizes[0] / 8;          // 65536
    dim3 grid(B / 4), block(256);           // one wave per ray, 4 waves/block
    hipLaunchKernelGGL(nerf_render, grid, block, 0, stream,
                       rays, u_coarse, u_fine, u_jitter, W1, b1, W2, b2, out);
}

// Round 8
// 75.138 us; speedup vs baseline: 1.5792x; 1.0789x over previous
//
#include <hip/hip_runtime.h>
#include <math.h>

// NeRF two-pass renderer. One wave (64 lanes) per ray; 4 waves per block.
// B=65536 rays, KC=64 coarse, KF=64 fine, HID=32.
//
// R8 = R7 + issue-count cuts:
//  - W2 staged in LDS (block-shared, single __syncthreads at start) -> no
//    per-call s_load/lgkmcnt interleave with a/c ds_reads.
//  - searchsorted 6 steps, no guards (cnt <= 63 provable).
//  - bitonic j=4/8/16 via ds_swizzle immediates; j=1,2 quad-perm DPP.
//  - 4-component output reductions via quad-transpose + row_ror + xor
//    (one tree instead of four scans); coalesced 8-dword store, lanes 0-7.
//  - sc/t = exp(-d*relu(sigma)) + 1e-10 computed directly.

typedef float f32x2 __attribute__((ext_vector_type(2)));
typedef _Float16 f16x2v __attribute__((ext_vector_type(2)));
typedef _Float16 f16x4v __attribute__((ext_vector_type(4)));

__device__ __forceinline__ float fast_rcp(float x) { return __builtin_amdgcn_rcpf(x); }
__device__ __forceinline__ float fsigmoid(float x) { return fast_rcp(1.0f + __expf(-x)); }

__device__ __forceinline__ f32x2 splat_lo(f32x2 v) { return __builtin_shufflevector(v, v, 0, 0); }
__device__ __forceinline__ f32x2 splat_hi(f32x2 v) { return __builtin_shufflevector(v, v, 1, 1); }

// compiler-only fence: no HW barrier; preserves LDS program order per wave
__device__ __forceinline__ void wave_fence() {
    asm volatile("" ::: "memory");
    __builtin_amdgcn_wave_barrier();
}

// DPP move: result = valid(src lane) ? shuffled x : oldv   (bound_ctrl=0)
template <int CTRL, int RMASK>
__device__ __forceinline__ float dpp_f(float x, float oldv) {
    return __int_as_float(__builtin_amdgcn_update_dpp(
        __float_as_int(oldv), __float_as_int(x), CTRL, RMASK, 0xf, false));
}
template <int CTRL, int RMASK>
__device__ __forceinline__ int dpp_i(int x, int oldv) {
    return __builtin_amdgcn_update_dpp(oldv, x, CTRL, RMASK, 0xf, false);
}
template <int OFF>
__device__ __forceinline__ float swz_f(float x) {
    return __int_as_float(__builtin_amdgcn_ds_swizzle(__float_as_int(x), OFF));
}

// inclusive multiply-scan over 64 lanes
__device__ __forceinline__ float scan_mul(float x) {
    x *= dpp_f<0x111, 0xf>(x, 1.0f);  // row_shr:1
    x *= dpp_f<0x112, 0xf>(x, 1.0f);  // row_shr:2
    x *= dpp_f<0x114, 0xf>(x, 1.0f);  // row_shr:4
    x *= dpp_f<0x118, 0xf>(x, 1.0f);  // row_shr:8
    x *= dpp_f<0x142, 0xa>(x, 1.0f);  // row_bcast:15 -> rows 1,3
    x *= dpp_f<0x143, 0xc>(x, 1.0f);  // row_bcast:31 -> rows 2,3
    return x;
}
// inclusive add-scan over 64 lanes; lane 63 holds the full sum
__device__ __forceinline__ float scan_add(float x) {
    x += dpp_f<0x111, 0xf>(x, 0.0f);
    x += dpp_f<0x112, 0xf>(x, 0.0f);
    x += dpp_f<0x114, 0xf>(x, 0.0f);
    x += dpp_f<0x118, 0xf>(x, 0.0f);
    x += dpp_f<0x142, 0xa>(x, 0.0f);
    x += dpp_f<0x143, 0xc>(x, 0.0f);
    return x;
}
__device__ __forceinline__ int scan_add_i(int x) {
    x += dpp_i<0x111, 0xf>(x, 0);
    x += dpp_i<0x112, 0xf>(x, 0);
    x += dpp_i<0x114, 0xf>(x, 0);
    x += dpp_i<0x118, 0xf>(x, 0);
    x += dpp_i<0x142, 0xa>(x, 0);
    x += dpp_i<0x143, 0xc>(x, 0);
    return x;
}

// 4-component wave reduction: every lane returns total of comp (lane&3).
__device__ __forceinline__ float quad_reduce4(float v0, float v1, float v2, float v3, int lane) {
    // stage xor1: comp bit0
    const bool b0 = (lane & 1) != 0;
    const float w01 = b0 ? v0 : v1, k01 = b0 ? v1 : v0;
    const float x01 = k01 + dpp_f<0xB1, 0xf>(w01, w01);   // quad_perm [1,0,3,2]
    const float w23 = b0 ? v2 : v3, k23 = b0 ? v3 : v2;
    const float x23 = k23 + dpp_f<0xB1, 0xf>(w23, w23);
    // stage xor2: comp bit1
    const bool b1 = (lane & 2) != 0;
    const float w = b1 ? x01 : x23, k = b1 ? x23 : x01;
    float x = k + dpp_f<0x4E, 0xf>(w, w);                 // quad_perm [2,3,0,1]
    // row reduce across the 4 quads of a 16-lane row
    x += dpp_f<0x124, 0xf>(x, x);                         // row_ror:4
    x += dpp_f<0x128, 0xf>(x, x);                         // row_ror:8
    // cross-row
    x += swz_f<0x401F>(x);                                // xor16 (within 32)
    x += __shfl_xor(x, 32);
    return x;
}

__global__ __launch_bounds__(256) void nerf_render(
    const float* __restrict__ rays,      // (B,8)  o(3) d(3) near far
    const float* __restrict__ u_coarse,  // (B,64)
    const float* __restrict__ u_fine,    // (B,64)
    const float* __restrict__ u_jitter,  // (B,64)
    const float* __restrict__ W1,        // (3,32)
    const float* __restrict__ b1,        // (32,)
    const float* __restrict__ W2,        // (32,4)
    const float* __restrict__ b2,        // (4,)
    float* __restrict__ out)             // (B,8)  rgb_f, depth_f, rgb_c, depth_c
{
    __shared__ f32x2  w2S[64];       // W2 pairs, block-shared          512B
    __shared__ float  acS[4][64];    // per wave: a[0..31], c[0..31]   1024B
    __shared__ float  zM[4][128];    // per wave merged z; hist overlay 2048B
    __shared__ f16x2v rgM[4][128];   // per wave merged (r,g)           2048B
    __shared__ f16x2v bsM[4][128];   // per wave merged (b,sigma)       2048B

    const int lane = threadIdx.x & 63;
    const int wv   = threadIdx.x >> 6;
    const int ray  = (blockIdx.x << 2) + wv;

    const float* rp = rays + ray * 8;
    const float ox = rp[0], oy = rp[1], oz = rp[2];
    const float ddx = rp[3], ddy = rp[4], ddz = rp[5];
    const float nearv = rp[6], farv = rp[7];

    // stage W2 into LDS (block-shared), then one block barrier
    if (threadIdx.x < 64) w2S[threadIdx.x] = reinterpret_cast<const f32x2*>(W2)[threadIdx.x];

    // cooperative a/c: lanes 0..31 -> a[j] = o@W1+b1, lanes 32..63 -> c[j] = d@W1
    {
        const int j = lane & 31;
        const float w0 = W1[j], w1 = W1[32 + j], w2 = W1[64 + j];
        const bool isA = lane < 32;
        const float px = isA ? ox : ddx;
        const float py = isA ? oy : ddy;
        const float pz = isA ? oz : ddz;
        const float bb = isA ? b1[j] : 0.0f;
        acS[wv][lane] = fmaf(px, w0, fmaf(py, w1, fmaf(pz, w2, bb)));
    }
    __syncthreads();  // covers w2S staging (once per kernel) + acS

    const float* aw = &acS[wv][0];
    const float* cw = &acS[wv][32];

    // h = relu(a + z*c) (32); out4 = h @ W2 + b2; rgb=sigmoid, sigma raw.
    auto mlp = [&](float z, float& rr, float& gg, float& bb_, float& sg) {
        const f32x2 zz = {z, z};
        const f32x2 zero2 = {0.0f, 0.0f};
        f32x2 acc01 = *reinterpret_cast<const f32x2*>(b2);
        f32x2 acc23 = *reinterpret_cast<const f32x2*>(b2 + 2);
#pragma unroll
        for (int j = 0; j < 32; j += 4) {
            const f32x2 a01 = *reinterpret_cast<const f32x2*>(aw + j);
            const f32x2 a23 = *reinterpret_cast<const f32x2*>(aw + j + 2);
            const f32x2 c01 = *reinterpret_cast<const f32x2*>(cw + j);
            const f32x2 c23 = *reinterpret_cast<const f32x2*>(cw + j + 2);
            f32x2 h01 = __builtin_elementwise_fma(zz, c01, a01);
            f32x2 h23 = __builtin_elementwise_fma(zz, c23, a23);
            h01 = __builtin_elementwise_max(h01, zero2);
            h23 = __builtin_elementwise_max(h23, zero2);
            {
                const f32x2 wA = w2S[(j + 0) * 2], wB = w2S[(j + 0) * 2 + 1];
                const f32x2 hs = splat_lo(h01);
                acc01 = __builtin_elementwise_fma(hs, wA, acc01);
                acc23 = __builtin_elementwise_fma(hs, wB, acc23);
            }
            {
                const f32x2 wA = w2S[(j + 1) * 2], wB = w2S[(j + 1) * 2 + 1];
                const f32x2 hs = splat_hi(h01);
                acc01 = __builtin_elementwise_fma(hs, wA, acc01);
                acc23 = __builtin_elementwise_fma(hs, wB, acc23);
            }
            {
                const f32x2 wA = w2S[(j + 2) * 2], wB = w2S[(j + 2) * 2 + 1];
                const f32x2 hs = splat_lo(h23);
                acc01 = __builtin_elementwise_fma(hs, wA, acc01);
                acc23 = __builtin_elementwise_fma(hs, wB, acc23);
            }
            {
                const f32x2 wA = w2S[(j + 3) * 2], wB = w2S[(j + 3) * 2 + 1];
                const f32x2 hs = splat_hi(h23);
                acc01 = __builtin_elementwise_fma(hs, wA, acc01);
                acc23 = __builtin_elementwise_fma(hs, wB, acc23);
            }
        }
        rr = fsigmoid(acc01.x); gg = fsigmoid(acc01.y);
        bb_ = fsigmoid(acc23.x); sg = acc23.y;
    };

    // ---------------- coarse pass ----------------
    const float uc = u_coarse[ray * 64 + lane];
    const float zsc = (float)lane * 0.015625f + uc * 0.015625f;  // bit-match ref
    const float zc = nearv * (1.0f - zsc) + farv * zsc;

    const float zcn = dpp_f<0x130, 0xf>(zc, zc);  // wave_shl:1 (lane i <- i+1)
    const float deltac = (lane == 63) ? (farv - zc) : (zcn - zc);

    float cr_, cg_, cb_, csig;
    mlp(zc, cr_, cg_, cb_, csig);
    const float ec = __expf(-deltac * fmaxf(csig, 0.0f));
    const float alphac = 1.0f - ec;
    const float sc = ec + 1e-10f;

    // exclusive prefix product -> transmittance (DPP scan + wave_shr:1)
    const float pincl = scan_mul(sc);
    const float Tc = dpp_f<0x138, 0xf>(pincl, 1.0f);  // lane0 keeps 1.0
    const float wc = alphac * Tc;

    // coarse outputs: one transposed reduction (comp = lane&3)
    const float coarseTot = quad_reduce4(wc * cr_, wc * cg_, wc * cb_, wc * zc, lane);

    // ---------------- fine sampling (inverse CDF, unnormalized) ----------------
    const float wp = wc + 1e-5f;
    const float cdf = scan_add(wp);  // inclusive prefix sum
    const float tot = __int_as_float(__builtin_amdgcn_readlane(__float_as_int(cdf), 63));

    const float uf = u_fine[ray * 64 + lane] * tot;  // unnormalized space; uf < tot
    // cnt = #{k: cdf_incl[k] <= u} in [0,63] -> 6 steps, no guards
    int cnt = 0;
#pragma unroll
    for (int step = 32; step >= 1; step >>= 1) {
        const float v = __shfl(cdf, cnt + step - 1);
        if (v <= uf) cnt += step;
    }
    const float uj = u_jitter[ray * 64 + lane];
    float key = (float)cnt + uj;  // == ref z_steps * 64 (bitwise)

    // ---------------- sort fine keys (bitonic, 64 lanes) ----------------
#pragma unroll
    for (int k = 2; k <= 64; k <<= 1) {
#pragma unroll
        for (int j = k >> 1; j > 0; j >>= 1) {
            float v;
            if (j == 1)       v = dpp_f<0xB1, 0xf>(key, key);   // quad_perm [1,0,3,2]
            else if (j == 2)  v = dpp_f<0x4E, 0xf>(key, key);   // quad_perm [2,3,0,1]
            else if (j == 4)  v = swz_f<0x101F>(key);           // ds_swizzle xor4
            else if (j == 8)  v = swz_f<0x201F>(key);           // xor8
            else if (j == 16) v = swz_f<0x401F>(key);           // xor16
            else              v = __shfl_xor(key, 32);
            const bool keepMin = (((lane & j) == 0) == ((lane & k) == 0));
            key = keepMin ? fminf(key, v) : fmaxf(key, v);
        }
    }

    // ---------------- analytic merge ranks (step-space) ----------------
    int cnti = (int)key; cnti = cnti > 63 ? 63 : cnti;
    const float ujr = key - (float)cnti;
    const float ucv = __shfl(uc, cnti);            // u_coarse[cnt'] (1 bpermute)
    const int g = cnti + ((ucv <= ujr) ? 1 : 0);   // fine k before coarse l <=> l >= g
    const int pos_f = lane + g;

    // pos_c = lane + #{k: g_k <= lane}: histogram overlaid on zM (pre-scatter)
    unsigned int* hist = reinterpret_cast<unsigned int*>(&zM[wv][0]);
    hist[lane] = 0u;
    wave_fence();
    atomicAdd(&hist[g], 1u);   // g==64 lands in zM slot 64 (overwritten later)
    wave_fence();
    const int cfv = scan_add_i((int)hist[lane]);  // inclusive: #{g <= lane}
    const int pos_c = lane + cfv;
    wave_fence();  // hist reads complete before zM scatter overwrites

    // fine z + MLP (coarse outputs reused, not recomputed)
    const float zsf = key * 0.015625f;
    const float zf = nearv * (1.0f - zsf) + farv * zsf;
    float fr_, fg_, fb_, fsig;
    mlp(zf, fr_, fg_, fb_, fsig);

    // ---------------- scatter merged (z f32; r,g,b,sigma f16) ----------------
    {
        zM[wv][pos_c] = zc;
        zM[wv][pos_f] = zf;
        f16x2v t;
        t.x = (_Float16)cr_;  t.y = (_Float16)cg_;  rgM[wv][pos_c] = t;
        t.x = (_Float16)fr_;  t.y = (_Float16)fg_;  rgM[wv][pos_f] = t;
        t.x = (_Float16)cb_;  t.y = (_Float16)csig; bsM[wv][pos_c] = t;
        t.x = (_Float16)fb_;  t.y = (_Float16)fsig; bsM[wv][pos_f] = t;
    }
    wave_fence();  // wave-private: scatter precedes gather in per-wave DS order

    // ---------------- fine composite (2 samples / lane) ----------------
    const float2 zz2 = *reinterpret_cast<const float2*>(&zM[wv][2 * lane]);
    const float z0 = zz2.x, z1 = zz2.y;
    const float z2n = zM[wv][(2 * lane + 2) & 127];
    const f16x4v rg4 = *reinterpret_cast<const f16x4v*>(&rgM[wv][2 * lane]);
    const f16x4v bs4 = *reinterpret_cast<const f16x4v*>(&bsM[wv][2 * lane]);
    const float r0 = (float)rg4.x, g0 = (float)rg4.y;
    const float r1 = (float)rg4.z, g1 = (float)rg4.w;
    const float b0 = (float)bs4.x, s0 = (float)bs4.y;
    const float b1v = (float)bs4.z, s1 = (float)bs4.w;

    const float d0 = z1 - z0;
    const float d1 = (lane == 63) ? (farv - z1) : (z2n - z1);

    const float e0 = __expf(-d0 * fmaxf(s0, 0.0f));
    const float e1 = __expf(-d1 * fmaxf(s1, 0.0f));
    const float al0 = 1.0f - e0;
    const float al1 = 1.0f - e1;
    const float t0 = e0 + 1e-10f;
    const float t1 = e1 + 1e-10f;

    // pair product, DPP inclusive scan, exclusive via wave_shr:1
    const float ppincl = scan_mul(t0 * t1);
    const float Te = dpp_f<0x138, 0xf>(ppincl, 1.0f);  // lane0 keeps 1.0
    const float w0 = al0 * Te;
    const float w1 = al1 * (Te * t0);

    // fine outputs: one transposed reduction (comp = lane&3)
    const float fineTot = quad_reduce4(fmaf(w0, r0, w1 * r1), fmaf(w0, g0, w1 * g1),
                                       fmaf(w0, b0, w1 * b1v), fmaf(w0, z0, w1 * z1), lane);

    // out layout: [rgb_f, depth_f, rgb_c, depth_c]; lanes 0..7 store one dword
    if (lane < 8) {
        out[ray * 8 + lane] = (lane < 4) ? fineTot : coarseTot;
    }
}

extern "C" void kernel_launch(void* const* d_in, const int* in_sizes, int n_in,
                              void* d_out, int out_size, void* d_ws, size_t ws_size,
                              hipStream_t stream) {
    const float* rays     = (const float*)d_in[0];
    const float* u_coarse = (const float*)d_in[1];
    const float* u_fine   = (const float*)d_in[2];
    const float* u_jitter = (const float*)d_in[3];
    const float* W1       = (const float*)d_in[4];
    const float* b1       = (const float*)d_in[5];
    const float* W2       = (const float*)d_in[6];
    const float* b2       = (const float*)d_in[7];
    float* out = (float*)d_out;

    const int B = in_sizes[0] / 8;          // 65536
    dim3 grid(B / 4), block(256);           // one wave per ray, 4 waves/block
    hipLaunchKernelGGL(nerf_render, grid, block, 0, stream,
                       rays, u_coarse, u_fine, u_jitter, W1, b1, W2, b2, out);
}